// Round 14
// baseline (370.810 us; speedup 1.0000x reference)
//
#include <hip/hip_runtime.h>
#include <math.h>

// EntNet forward on MI355X.
// Sizes: VOC=32000, MEM=128, NSLOTS=20, NSENT=128, MAXLEN=32, QLEN=16, ANSLEN=8, B=64
//
// R13 (best, 244us scan): single-plane bf16 weights, bf16 state plane, fp32
// register recurrence, 2 barriers, 512 thr. Step 4584 cyc, VALU ~50% of
// busy-CU time, rest latency at 2 waves/SIMD.
// R14 = R13 + wave specialization at 1024 thr (4 waves/SIMD): waves 0-7 =
// MFMA+update (b_h 32 regs + xprev 16 + acc 32 AGPR), waves 8-15 = gate +
// s/sk prefetch. To fit the 128-reg/wave budget (R8's spill was with 64-reg
// dual-plane weights + perms), s and Ws planes are bf16 (prep writes sTb16/
// WsTb16; 2^-8 relative on those terms — 9 rounds at absmax 0.0 say fine).
// Union of loop-carried regs ~78 arch + 32 AGPR = 110 < 128.
// Spill tripwire: WRITE_SIZE (640KB clean; MBs = scratch -> revert to R13).

typedef __attribute__((ext_vector_type(8)))  short bf16x8;
typedef __attribute__((ext_vector_type(16))) float f32x16;

__device__ __forceinline__ unsigned short f2bh(float x) {   // f32 -> bf16 RNE
    unsigned int u = __float_as_uint(x);
    u += 0x7FFFu + ((u >> 16) & 1u);
    return (unsigned short)(u >> 16);
}
__device__ __forceinline__ float bh2f(unsigned short h) {
    return __uint_as_float(((unsigned int)h) << 16);
}
// u32 holding two bf16 (little-endian): low 16 = element 2i, high = 2i+1
__device__ __forceinline__ float blo(unsigned int w) { return __uint_as_float(w << 16); }
__device__ __forceinline__ float bhi(unsigned int w) { return __uint_as_float(w & 0xFFFF0000u); }

// ---------------------------------------------------------------- prep
__global__ __launch_bounds__(128) void prep_kernel(
    const int* __restrict__ ids, const int* __restrict__ ques, const int* __restrict__ ans,
    const float* __restrict__ E, const float* __restrict__ Ww, const float* __restrict__ Wb,
    const float* __restrict__ Vw, const float* __restrict__ Vb, const float* __restrict__ skeys,
    unsigned short* __restrict__ sTb16, unsigned short* __restrict__ WsTb16,
    float* __restrict__ vkey, float* __restrict__ qv, float* __restrict__ a1v,
    float* __restrict__ a2v, float* __restrict__ SK)
{
    const int bi  = blockIdx.x;
    const int tid = threadIdx.x;   // 128
    __shared__ float s_l[8][132];
    __shared__ float sk_l[20 * 132];
    __shared__ float k_l[128];
    if (bi < 1024) {
        const int b = bi >> 4;
        const int g = bi & 15;
        for (int r = tid; r < 2560; r += 128) sk_l[(r >> 7) * 132 + (r & 127)] = skeys[r];
        for (int tt = 0; tt < 8; ++tt) {
            const int t     = g * 8 + tt;
            const int token = ids[b * 4096 + t];
            const float v   = E[token * 128 + tid];
            s_l[tt][tid] = v;
            sTb16[(t * 64 + b) * 128 + tid] = f2bh(v);    // bf16 plane, (t,b,m)
        }
        __syncthreads();
        // Ws rows
        float acc[8];
        const float wbn = Wb[tid];
        #pragma unroll
        for (int i = 0; i < 8; ++i) acc[i] = wbn;
        const float4* wrow = (const float4*)(Ww + tid * 128);
        for (int m4 = 0; m4 < 32; ++m4) {
            const float4 w = wrow[m4];
            #pragma unroll
            for (int tt = 0; tt < 8; ++tt) {
                acc[tt] += s_l[tt][m4*4+0]*w.x + s_l[tt][m4*4+1]*w.y
                         + s_l[tt][m4*4+2]*w.z + s_l[tt][m4*4+3]*w.w;
            }
        }
        for (int tt = 0; tt < 8; ++tt)
            WsTb16[((g*8+tt) * 64 + b) * 128 + tid] = f2bh(acc[tt]);   // bf16, (t,b,n)
        // SK[j][t][b] = dot(s_t[b], skeys[j])  (gate key-dot, fp32, hoisted)
        for (int idx = tid; idx < 160; idx += 128) {
            const int tt = idx / 20;
            const int jj = idx - tt * 20;
            float d = 0.f;
            for (int m = 0; m < 128; ++m) d += s_l[tt][m] * sk_l[jj * 132 + m];
            SK[(jj * 128 + (g*8 + tt)) * 64 + b] = d;
        }
    } else if (bi < 1044) {
        const int j = bi - 1024;
        k_l[tid] = skeys[j * 128 + tid];
        __syncthreads();
        float acc = Vb[tid];
        const float4* vrow = (const float4*)(Vw + tid * 128);
        for (int m4 = 0; m4 < 32; ++m4) {
            const float4 w = vrow[m4];
            acc += k_l[m4*4]*w.x + k_l[m4*4+1]*w.y + k_l[m4*4+2]*w.z + k_l[m4*4+3]*w.w;
        }
        vkey[j * 128 + tid] = acc;
    } else {
        const int b = bi - 1044;
        float sq = 0.f, s1 = 0.f, s2 = 0.f;
        for (int i = 0; i < 16; ++i) sq += E[ques[b*16+i] * 128 + tid];
        for (int i = 0; i < 8;  ++i) s1 += E[ans[(b*8+i)*2+0] * 128 + tid];
        for (int i = 0; i < 8;  ++i) s2 += E[ans[(b*8+i)*2+1] * 128 + tid];
        qv [b*128+tid] = sq * (1.f/16.f);
        a1v[b*128+tid] = s1 * 0.125f;
        a2v[b*128+tid] = s2 * 0.125f;
    }
}

// ---------------------------------------------------------------- scan (specialized, MFMA 32x32)
// One block per slot j. 1024 threads = 16 waves, 4 waves/SIMD (128 regs/wave).
// Compute waves 0-7: one 32x32 C tile each (bt2 = wave&1, nt2 = wave>>1).
//   Weights b_h (bf16 RNE of Uw rows) in 32 VGPRs. State AB bf16[64][136],
//   fragment-ready A reads (1 ds_read_b128/kc). 8 MFMAs, 2x4-deep chains.
//   fp32 recurrence xprev[16] in regs; Ws term from bf16 WsTb16 (8 u32 regs).
// Gate waves 8-15: g[b] = sigmoid(inv*dot(s_t[b],U[b]) + SK[j][t][b]) with
//   bf16 s (8 u32 regs); writes g_l pre-B1; prefetches s/sk post-B1.
// inv_s: all waves read wred at top (written post-B1 prev step, visible after
// B2; write-after-read separated by B1). 2 barriers/step.
// C/D layout [m74/m101]: col = lane&31, row = (reg&3)+8*(reg>>2)+4*(lane>>5).
__global__ __launch_bounds__(1024, 1) void scan_kernel(
    const unsigned short* __restrict__ sTb16, const unsigned short* __restrict__ WsTb16,
    const float* __restrict__ vkey, const float* __restrict__ Uw,
    const float* __restrict__ Ub, const float* __restrict__ SK,
    float* __restrict__ h_out)
{
    __shared__ unsigned short AB[64 * 136];   // bf16 state, stride 136 (272B rows)
    __shared__ float g_l[64];
    __shared__ float wred[8];

    const int j    = blockIdx.x;
    const int tid  = threadIdx.x;        // 1024
    const int wave = tid >> 6;           // 0..15
    const int lane = tid & 63;
    const bool is_compute = (wave < 8);

    // compute-wave coords
    const int l32  = lane & 31;
    const int q    = lane >> 5;          // 0..1
    const int bt2  = wave & 1;           // b half
    const int nt2  = (wave >> 1) & 3;    // n quarter
    const int n    = nt2 * 32 + l32;     // owned output column

    // gate-wave coords
    const int gtid = tid - 512;          // 0..511
    const int gb   = (gtid >> 3) & 63;   // batch row
    const int gm   = (gtid & 7) * 16;    // m-slice (16 bf16)

    // ---- one-time init ----
    bf16x8 b_h[8];
    float  ubv = 0.f;
    if (is_compute) {
        const int k0 = q * 8;
        #pragma unroll
        for (int kc = 0; kc < 8; ++kc) {
            const float4* src = (const float4*)(Uw + n * 128 + kc * 16 + k0);
            const float4 v0 = src[0], v1 = src[1];
            const float xs[8] = {v0.x,v0.y,v0.z,v0.w, v1.x,v1.y,v1.z,v1.w};
            #pragma unroll
            for (int e = 0; e < 8; ++e) b_h[kc][e] = (short)f2bh(xs[e]);
        }
        ubv = Ub[n] + vkey[j * 128 + n];
    }
    for (int i = tid; i < 64 * 136 / 2; i += 1024) ((unsigned int*)AB)[i] = 0u;
    if (tid < 8) wred[tid] = 0.125f;     // sum = 1 -> first inv_s = 1 (state = 0)

    // loop-carried registers (per role)
    float xprev[16];
    unsigned int wsb[8];                 // 16 bf16 Ws values (compute)
    unsigned int sgv[8];                 // 16 bf16 s values (gate)
    float skv = 0.f;
    if (is_compute) {
        #pragma unroll
        for (int r = 0; r < 16; ++r) xprev[r] = 0.f;
        #pragma unroll
        for (int g4 = 0; g4 < 4; ++g4) {
            // wsb pair order matches update order r = g4*4..g4*4+3 via brow map
            const int brow0 = bt2*32 + 4*q + (g4 & 1) + 8*(g4 >> 1);   // placeholder unused
            (void)brow0;
        }
        // load Ws for the 16 owned (brow, n) cells: rows brow(r), col n, bf16
        #pragma unroll
        for (int r2 = 0; r2 < 8; ++r2) {
            const int r = r2 * 2;
            const int brow = bt2*32 + 4*q + (r & 3) + 8*(r >> 2);
            // cells (brow, n) and (brow+1, n) are NOT adjacent in memory ->
            // load 2 singles packed manually
            const unsigned short w0 = WsTb16[(0*64 + brow)*128 + n];
            const int browb = bt2*32 + 4*q + ((r+1) & 3) + 8*((r+1) >> 2);
            const unsigned short w1 = WsTb16[(0*64 + browb)*128 + n];
            wsb[r2] = (unsigned int)w0 | ((unsigned int)w1 << 16);
        }
    } else {
        const unsigned short* sp = sTb16 + (0*64 + gb)*128 + gm;
        const uint4* s4 = (const uint4*)sp;
        const uint4 a = s4[0], b2 = s4[1];
        sgv[0]=a.x; sgv[1]=a.y; sgv[2]=a.z; sgv[3]=a.w;
        sgv[4]=b2.x; sgv[5]=b2.y; sgv[6]=b2.z; sgv[7]=b2.w;
        skv = SK[(j*128 + 0)*64 + gb];
    }
    __syncthreads();

    for (int t = 0; t < 128; ++t) {
        // ---- all waves: inv_s (wred written post-B1 prev step; B1 separates
        //      this read from this step's writes) ----
        const float4 w0 = *(const float4*)(wred);
        const float4 w1 = *(const float4*)(wred + 4);
        const float inv_s = 1.f / sqrtf(w0.x+w0.y+w0.z+w0.w + w1.x+w1.y+w1.z+w1.w);

        f32x16 acc0 = {0.f,0.f,0.f,0.f,0.f,0.f,0.f,0.f,
                       0.f,0.f,0.f,0.f,0.f,0.f,0.f,0.f};
        f32x16 acc1 = acc0;
        if (is_compute) {
            // ---- MFMA: 8 insts, 2 independent 4-deep chains ----
            const unsigned short* arow = AB + (bt2*32 + l32) * 136 + q * 8;
            #pragma unroll
            for (int kc = 0; kc < 8; ++kc) {
                const bf16x8 a = *(const bf16x8*)(arow + kc * 16);
                if (kc & 1) acc1 = __builtin_amdgcn_mfma_f32_32x32x16_bf16(a, b_h[kc], acc1, 0, 0, 0);
                else        acc0 = __builtin_amdgcn_mfma_f32_32x32x16_bf16(a, b_h[kc], acc0, 0, 0, 0);
            }
        } else {
            // ---- gate: d1 = dot(s_t[gb], U[gb]) over 16-elem slice ----
            const uint4* u4 = (const uint4*)(AB + gb * 136 + gm);
            const uint4 a = u4[0], b2 = u4[1];
            float d1 = blo(sgv[0])*blo(a.x)  + bhi(sgv[0])*bhi(a.x)
                     + blo(sgv[1])*blo(a.y)  + bhi(sgv[1])*bhi(a.y)
                     + blo(sgv[2])*blo(a.z)  + bhi(sgv[2])*bhi(a.z)
                     + blo(sgv[3])*blo(a.w)  + bhi(sgv[3])*bhi(a.w)
                     + blo(sgv[4])*blo(b2.x) + bhi(sgv[4])*bhi(b2.x)
                     + blo(sgv[5])*blo(b2.y) + bhi(sgv[5])*bhi(b2.y)
                     + blo(sgv[6])*blo(b2.z) + bhi(sgv[6])*bhi(b2.z)
                     + blo(sgv[7])*blo(b2.w) + bhi(sgv[7])*bhi(b2.w);
            d1 += __shfl_xor(d1, 1, 64);
            d1 += __shfl_xor(d1, 2, 64);
            d1 += __shfl_xor(d1, 4, 64);
            if ((gtid & 7) == 0) g_l[gb] = 1.f / (1.f + expf(-(inv_s * d1 + skv)));
        }
        __syncthreads();   // B1: AB reads done (both roles); g_l visible

        if (is_compute) {
            // ---- update owned (b, n) cells in C layout ----
            const float4 gA = *(const float4*)(g_l + bt2*32 + 4*q + 0);
            const float4 gB = *(const float4*)(g_l + bt2*32 + 4*q + 8);
            const float4 gC = *(const float4*)(g_l + bt2*32 + 4*q + 16);
            const float4 gD = *(const float4*)(g_l + bt2*32 + 4*q + 24);
            const float gr[16] = {gA.x,gA.y,gA.z,gA.w, gB.x,gB.y,gB.z,gB.w,
                                  gC.x,gC.y,gC.z,gC.w, gD.x,gD.y,gD.z,gD.w};
            float ssq = 0.f;
            #pragma unroll
            for (int r = 0; r < 16; ++r) {
                const int brow = bt2*32 + 4*q + (r & 3) + 8*(r >> 2);
                const float ws = (r & 1) ? bhi(wsb[r >> 1]) : blo(wsb[r >> 1]);
                float hr = fmaf(inv_s, acc0[r] + acc1[r], ubv + ws);
                hr = fmaxf(hr, 0.f);                          // h_cand
                const float x = fmaf(inv_s, xprev[r], gr[r] * hr);
                xprev[r] = x;                                 // fp32 recurrence
                AB[brow*136 + n] = f2bh(x);                   // bf16 matmul plane
                ssq = fmaf(x, x, ssq);
            }
            // prefetch Ws (t+1), drains by first use next step
            {
                const int tn = (t < 127) ? t + 1 : 0;
                #pragma unroll
                for (int r2 = 0; r2 < 8; ++r2) {
                    const int r = r2 * 2;
                    const int brow  = bt2*32 + 4*q + (r & 3) + 8*(r >> 2);
                    const int browb = bt2*32 + 4*q + ((r+1) & 3) + 8*((r+1) >> 2);
                    const unsigned short v0 = WsTb16[(tn*64 + brow )*128 + n];
                    const unsigned short v1 = WsTb16[(tn*64 + browb)*128 + n];
                    wsb[r2] = (unsigned int)v0 | ((unsigned int)v1 << 16);
                }
            }
            #pragma unroll
            for (int m = 1; m < 64; m <<= 1) ssq += __shfl_xor(ssq, m, 64);
            if (lane == 0) wred[wave] = ssq;
        } else {
            // prefetch gate inputs for t+1
            const int tn = (t < 127) ? t + 1 : 0;
            const uint4* s4 = (const uint4*)(sTb16 + (tn*64 + gb)*128 + gm);
            const uint4 a = s4[0], b2 = s4[1];
            sgv[0]=a.x; sgv[1]=a.y; sgv[2]=a.z; sgv[3]=a.w;
            sgv[4]=b2.x; sgv[5]=b2.y; sgv[6]=b2.z; sgv[7]=b2.w;
            skv = SK[(j*128 + tn)*64 + gb];
        }
        __syncthreads();   // B2: AB writes + wred visible
    }

    // ---- h = inv * state (fp32 path), layout (b, j, m) ----
    const float4 f0 = *(const float4*)(wred);
    const float4 f1 = *(const float4*)(wred + 4);
    const float invf = 1.f / sqrtf(f0.x+f0.y+f0.z+f0.w + f1.x+f1.y+f1.z+f1.w);
    if (is_compute) {
        #pragma unroll
        for (int r = 0; r < 16; ++r) {
            const int brow = bt2*32 + 4*q + (r & 3) + 8*(r >> 2);
            h_out[(brow*20 + j)*128 + n] = invf * xprev[r];
        }
    }
}

// ---------------------------------------------------------------- final
__global__ __launch_bounds__(128) void final_kernel(
    const float* __restrict__ h, const float* __restrict__ qv,
    const float* __restrict__ a1v, const float* __restrict__ a2v,
    const float* __restrict__ Hw, const float* __restrict__ Hb,
    float* __restrict__ out)
{
    const int b   = blockIdx.x;
    const int tid = threadIdx.x;    // 128
    __shared__ float hb[20][128];
    __shared__ float ql[128];
    __shared__ float ul[128];
    __shared__ float pl[20];
    __shared__ float lgt[20];
    __shared__ float red1[2], red2[2];

    for (int jj = 0; jj < 20; ++jj) hb[jj][tid] = h[(b*20+jj)*128 + tid];
    ql[tid] = qv[b*128 + tid];
    __syncthreads();
    if (tid < 20) {
        float d = 0.f;
        for (int m = 0; m < 128; ++m) d += hb[tid][m] * ql[m];
        lgt[tid] = d;
    }
    __syncthreads();
    if (tid == 0) {
        float mx = lgt[0];
        for (int jj = 1; jj < 20; ++jj) mx = fmaxf(mx, lgt[jj]);
        float s = 0.f;
        for (int jj = 0; jj < 20; ++jj) { const float e = expf(lgt[jj]-mx); pl[jj] = e; s += e; }
        const float is = 1.f / s;
        for (int jj = 0; jj < 20; ++jj) pl[jj] *= is;
    }
    __syncthreads();
    float u = 0.f;
    for (int jj = 0; jj < 20; ++jj) u += pl[jj] * hb[jj][tid];
    ul[tid] = u;
    __syncthreads();
    float acc = ql[tid] + Hb[tid];
    const float4* hwr = (const float4*)(Hw + tid*128);
    for (int m4 = 0; m4 < 32; ++m4) {
        const float4 w = hwr[m4];
        acc += ul[m4*4]*w.x + ul[m4*4+1]*w.y + ul[m4*4+2]*w.z + ul[m4*4+3]*w.w;
    }
    const float r  = fmaxf(acc, 0.f);
    float y1 = r * a1v[b*128+tid];
    float y2 = r * a2v[b*128+tid];
    #pragma unroll
    for (int mask = 1; mask < 64; mask <<= 1) {
        y1 += __shfl_xor(y1, mask, 64);
        y2 += __shfl_xor(y2, mask, 64);
    }
    if ((tid & 63) == 0) { red1[tid>>6] = y1; red2[tid>>6] = y2; }
    __syncthreads();
    if (tid == 0) {
        const float z1 = red1[0] + red1[1];
        const float z2 = red2[0] + red2[1];
        const float mx = fmaxf(z1, z2);
        const float e1 = expf(z1-mx), e2 = expf(z2-mx);
        const float s  = e1 + e2;
        out[b*2+0] = e1 / s;
        out[b*2+1] = e2 / s;
    }
}

// ---------------------------------------------------------------- launch
extern "C" void kernel_launch(void* const* d_in, const int* in_sizes, int n_in,
                              void* d_out, int out_size, void* d_ws, size_t ws_size,
                              hipStream_t stream)
{
    const int*   ids  = (const int*)  d_in[0];
    const int*   ques = (const int*)  d_in[1];
    const int*   ans  = (const int*)  d_in[2];
    const float* E    = (const float*)d_in[3];
    const float* Uw   = (const float*)d_in[4];
    const float* Ubv  = (const float*)d_in[5];
    const float* Vw   = (const float*)d_in[6];
    const float* Vb   = (const float*)d_in[7];
    const float* Ww   = (const float*)d_in[8];
    const float* Wb   = (const float*)d_in[9];
    const float* sk   = (const float*)d_in[10];
    const float* Hw   = (const float*)d_in[11];
    const float* Hb   = (const float*)d_in[12];

    // workspace (float slots): sTb16 512K | WsTb16 512K | vkey 2560
    // | qv/a1v/a2v 3*8192 | h 163840 | SK 163840   (~4.8 MB)
    float* ws    = (float*)d_ws;
    unsigned short* sTb16  = (unsigned short*)ws;
    unsigned short* WsTb16 = (unsigned short*)(ws + 524288);
    float* vkey  = ws + 1048576;
    float* qv    = vkey + 2560;
    float* a1v   = qv  + 8192;
    float* a2v   = a1v + 8192;
    float* h     = a2v + 8192;
    float* SK    = h   + 163840;

    prep_kernel<<<1108, 128, 0, stream>>>(ids, ques, ans, E, Ww, Wb, Vw, Vb, sk,
                                          sTb16, WsTb16, vkey, qv, a1v, a2v, SK);
    scan_kernel<<<20, 1024, 0, stream>>>(sTb16, WsTb16, vkey, Uw, Ubv, SK, h);
    final_kernel<<<64, 128, 0, stream>>>(h, qv, a1v, a2v, Hw, Hb, (float*)d_out);
}

// Round 15
// 342.638 us; speedup vs baseline: 1.0822x; 1.0822x over previous
//
#include <hip/hip_runtime.h>
#include <math.h>

// EntNet forward on MI355X.
// Sizes: VOC=32000, MEM=128, NSLOTS=20, NSENT=128, MAXLEN=32, QLEN=16, ANSLEN=8, B=64
//
// R14 post-mortem: wave specialization regressed even WITHOUT spilling ->
// 5 structural variants (R9/R11/R12/R14) all lose to the R10/R13 line; the
// only post-R10 win was R13's work-halving on the unchanged structure.
// R15 = R13 byte-exact + three chain micro-trims (no structural change):
//  (1) truncation pack for the bf16 state plane (1 op vs 3; fp32 recurrence
//      carries precision, absmax margin huge),
//  (2) inv_s via v_rsq_f32 (drops refine sequence off the step head),
//  (3) gate sigmoid via __expf + v_rcp_f32 (drops division fixup off the
//      gate->g_l->B1 chain).

typedef __attribute__((ext_vector_type(8)))  short bf16x8;
typedef __attribute__((ext_vector_type(16))) float f32x16;

__device__ __forceinline__ unsigned short f2bh(float x) {   // f32 -> bf16 RNE
    unsigned int u = __float_as_uint(x);
    u += 0x7FFFu + ((u >> 16) & 1u);
    return (unsigned short)(u >> 16);
}
__device__ __forceinline__ float bh2f(unsigned short h) {
    return __uint_as_float(((unsigned int)h) << 16);
}
// u32 holding two bf16 (little-endian): low 16 = element 2i, high = 2i+1
__device__ __forceinline__ float blo(unsigned int w) { return __uint_as_float(w << 16); }
__device__ __forceinline__ float bhi(unsigned int w) { return __uint_as_float(w & 0xFFFF0000u); }

// ---------------------------------------------------------------- prep
__global__ __launch_bounds__(128) void prep_kernel(
    const int* __restrict__ ids, const int* __restrict__ ques, const int* __restrict__ ans,
    const float* __restrict__ E, const float* __restrict__ Ww, const float* __restrict__ Wb,
    const float* __restrict__ Vw, const float* __restrict__ Vb, const float* __restrict__ skeys,
    float* __restrict__ sT, float* __restrict__ WsT, float* __restrict__ vkey,
    float* __restrict__ qv, float* __restrict__ a1v, float* __restrict__ a2v,
    float* __restrict__ SK)
{
    const int bi  = blockIdx.x;
    const int tid = threadIdx.x;   // 128
    __shared__ float s_l[8][132];
    __shared__ float sk_l[20 * 132];
    __shared__ float k_l[128];
    if (bi < 1024) {
        const int b = bi >> 4;
        const int g = bi & 15;
        for (int r = tid; r < 2560; r += 128) sk_l[(r >> 7) * 132 + (r & 127)] = skeys[r];
        for (int tt = 0; tt < 8; ++tt) {
            const int t     = g * 8 + tt;
            const int token = ids[b * 4096 + t];
            const float v   = E[token * 128 + tid];
            s_l[tt][tid] = v;
            sT[(t * 64 + b) * 128 + tid] = v;         // layout (t, b, m)
        }
        __syncthreads();
        // Ws rows
        float acc[8];
        const float wbn = Wb[tid];
        #pragma unroll
        for (int i = 0; i < 8; ++i) acc[i] = wbn;
        const float4* wrow = (const float4*)(Ww + tid * 128);
        for (int m4 = 0; m4 < 32; ++m4) {
            const float4 w = wrow[m4];
            #pragma unroll
            for (int tt = 0; tt < 8; ++tt) {
                acc[tt] += s_l[tt][m4*4+0]*w.x + s_l[tt][m4*4+1]*w.y
                         + s_l[tt][m4*4+2]*w.z + s_l[tt][m4*4+3]*w.w;
            }
        }
        for (int tt = 0; tt < 8; ++tt)
            WsT[((g*8+tt) * 64 + b) * 128 + tid] = acc[tt];     // layout (t, b, n)
        // SK[j][t][b] = dot(s_t[b], skeys[j])  (gate key-dot, hoisted from scan)
        for (int idx = tid; idx < 160; idx += 128) {
            const int tt = idx / 20;
            const int jj = idx - tt * 20;
            float d = 0.f;
            for (int m = 0; m < 128; ++m) d += s_l[tt][m] * sk_l[jj * 132 + m];
            SK[(jj * 128 + (g*8 + tt)) * 64 + b] = d;
        }
    } else if (bi < 1044) {
        const int j = bi - 1024;
        k_l[tid] = skeys[j * 128 + tid];
        __syncthreads();
        float acc = Vb[tid];
        const float4* vrow = (const float4*)(Vw + tid * 128);
        for (int m4 = 0; m4 < 32; ++m4) {
            const float4 w = vrow[m4];
            acc += k_l[m4*4]*w.x + k_l[m4*4+1]*w.y + k_l[m4*4+2]*w.z + k_l[m4*4+3]*w.w;
        }
        vkey[j * 128 + tid] = acc;
    } else {
        const int b = bi - 1044;
        float sq = 0.f, s1 = 0.f, s2 = 0.f;
        for (int i = 0; i < 16; ++i) sq += E[ques[b*16+i] * 128 + tid];
        for (int i = 0; i < 8;  ++i) s1 += E[ans[(b*8+i)*2+0] * 128 + tid];
        for (int i = 0; i < 8;  ++i) s2 += E[ans[(b*8+i)*2+1] * 128 + tid];
        qv [b*128+tid] = sq * (1.f/16.f);
        a1v[b*128+tid] = s1 * 0.125f;
        a2v[b*128+tid] = s2 * 0.125f;
    }
}

// ---------------------------------------------------------------- scan (MFMA 32x32, bf16 state)
// One block per slot j. 512 threads = 8 waves, 2 waves/SIMD (256 regs/wave).
// Each wave owns ONE 32x32 C tile (bt2 = wave&1, nt2 = wave>>1).
//   Weights b_h (bf16 RNE of Uw) in 32 VGPRs, loaded once. Single plane (R13).
//   State AB: bf16[64][136] in LDS, fragment-ready (A-frag = 1 ds_read_b128/kc).
//   fp32 recurrence xprev[16] in registers; only matmul/gate INPUT rounded.
//   8 MFMAs, 2 independent 4-deep chains by kc parity.
// C/D layout [m74/m101]: col = lane&31, row = (reg&3)+8*(reg>>2)+4*(lane>>5).
// Prefetch for t+1 in the update phase (R10-proven placement). 2 barriers/step.
__global__ __launch_bounds__(512, 1) void scan_kernel(
    const float* __restrict__ sT, const float* __restrict__ WsT,
    const float* __restrict__ vkey, const float* __restrict__ Uw,
    const float* __restrict__ Ub, const float* __restrict__ SK,
    float* __restrict__ h_out)
{
    __shared__ unsigned short AB[64 * 136];   // bf16 state, stride 136 (272B rows)
    __shared__ float g_l[64];
    __shared__ float wred[8];

    const int j    = blockIdx.x;
    const int tid  = threadIdx.x;        // 512
    const int wave = tid >> 6;           // 0..7
    const int lane = tid & 63;
    const int l32  = lane & 31;
    const int q    = lane >> 5;          // 0..1
    const int bt2  = wave & 1;           // b half
    const int nt2  = wave >> 1;          // n quarter
    const int n    = nt2 * 32 + l32;     // owned output column
    const int gb   = tid >> 3;           // gate: batch row 0..63
    const int gm   = (tid & 7) * 16;     // gate: m-slice (16 bf16)

    // ---- one-time: weight fragments -> 32 VGPRs (single bf16 plane, RNE) ----
    bf16x8 b_h[8];
    {
        const int k0 = q * 8;
        #pragma unroll
        for (int kc = 0; kc < 8; ++kc) {
            const float4* src = (const float4*)(Uw + n * 128 + kc * 16 + k0);
            const float4 v0 = src[0], v1 = src[1];
            const float xs[8] = {v0.x,v0.y,v0.z,v0.w, v1.x,v1.y,v1.z,v1.w};
            #pragma unroll
            for (int e = 0; e < 8; ++e) b_h[kc][e] = (short)f2bh(xs[e]);
        }
    }
    for (int i = tid; i < 64 * 136 / 2; i += 512) ((unsigned int*)AB)[i] = 0u;
    const float ubv = Ub[n] + vkey[j * 128 + n];

    // fp32 recurrence state (C layout), registers across steps
    float xprev[16];
    #pragma unroll
    for (int r = 0; r < 16; ++r) xprev[r] = 0.f;

    // ---- current-step globals (t = 0) ----
    float4 sv0, sv1, sv2, sv3;
    float  skv;
    float  wsv[16];
    {
        const float4* s4 = (const float4*)(sT + (0*64 + gb)*128 + gm);
        sv0 = s4[0]; sv1 = s4[1]; sv2 = s4[2]; sv3 = s4[3];
        skv = SK[(j*128 + 0)*64 + gb];
        #pragma unroll
        for (int r = 0; r < 16; ++r) {
            const int brow = bt2*32 + 4*q + (r & 3) + 8*(r >> 2);
            wsv[r] = WsT[(0*64 + brow)*128 + n];
        }
    }
    __syncthreads();

    float inv_s = 1.f;                   // true mem = inv_s * bf16(state)

    for (int t = 0; t < 128; ++t) {
        // ---- gate: g[b] = sigmoid(inv*dot(s_t[b],U[b]) + SK[j][t][b]) ----
        {
            const uint4* u4 = (const uint4*)(AB + gb * 136 + gm);   // 272B rows: aligned
            const uint4 w0 = u4[0], w1 = u4[1];                     // 16 bf16
            float d1 = sv0.x*blo(w0.x) + sv0.y*bhi(w0.x)
                     + sv0.z*blo(w0.y) + sv0.w*bhi(w0.y)
                     + sv1.x*blo(w0.z) + sv1.y*bhi(w0.z)
                     + sv1.z*blo(w0.w) + sv1.w*bhi(w0.w)
                     + sv2.x*blo(w1.x) + sv2.y*bhi(w1.x)
                     + sv2.z*blo(w1.y) + sv2.w*bhi(w1.y)
                     + sv3.x*blo(w1.z) + sv3.y*bhi(w1.z)
                     + sv3.z*blo(w1.w) + sv3.w*bhi(w1.w);
            d1 += __shfl_xor(d1, 1, 64);
            d1 += __shfl_xor(d1, 2, 64);
            d1 += __shfl_xor(d1, 4, 64);
            if ((tid & 7) == 0) {
                const float e = __expf(-(inv_s * d1 + skv));
                g_l[gb] = __builtin_amdgcn_rcpf(1.f + e);   // fast sigmoid
            }
        }

        // ---- MFMA: acc = U(32b x 128m) . W(32n x 128m)^T, 2x4-deep chains ----
        f32x16 acc0 = {0.f,0.f,0.f,0.f,0.f,0.f,0.f,0.f,
                       0.f,0.f,0.f,0.f,0.f,0.f,0.f,0.f};
        f32x16 acc1 = acc0;
        {
            const unsigned short* arow = AB + (bt2*32 + l32) * 136 + q * 8;
            #pragma unroll
            for (int kc = 0; kc < 8; ++kc) {
                const bf16x8 a = *(const bf16x8*)(arow + kc * 16);   // fragment-ready
                if (kc & 1) acc1 = __builtin_amdgcn_mfma_f32_32x32x16_bf16(a, b_h[kc], acc1, 0, 0, 0);
                else        acc0 = __builtin_amdgcn_mfma_f32_32x32x16_bf16(a, b_h[kc], acc0, 0, 0, 0);
            }
        }
        __syncthreads();   // B1: AB reads complete; g_l visible

        // ---- update owned (b, n) cells in C layout ----
        const float4 gA = *(const float4*)(g_l + bt2*32 + 4*q + 0);
        const float4 gB = *(const float4*)(g_l + bt2*32 + 4*q + 8);
        const float4 gC = *(const float4*)(g_l + bt2*32 + 4*q + 16);
        const float4 gD = *(const float4*)(g_l + bt2*32 + 4*q + 24);
        const float gr[16] = {gA.x,gA.y,gA.z,gA.w, gB.x,gB.y,gB.z,gB.w,
                              gC.x,gC.y,gC.z,gC.w, gD.x,gD.y,gD.z,gD.w};
        float ssq = 0.f;
        #pragma unroll
        for (int r = 0; r < 16; ++r) {
            const int brow = bt2*32 + 4*q + (r & 3) + 8*(r >> 2);
            float hr = fmaf(inv_s, acc0[r] + acc1[r], ubv + wsv[r]);
            hr = fmaxf(hr, 0.f);                          // h_cand
            const float x = fmaf(inv_s, xprev[r], gr[r] * hr);
            xprev[r] = x;                                 // fp32 recurrence
            AB[brow*136 + n] = (unsigned short)(__float_as_uint(x) >> 16);  // trunc pack
            ssq = fmaf(x, x, ssq);
        }

        // ---- prefetch t+1 globals (R10 placement: overlaps shuffles + B2) ----
        {
            const int tn = (t < 127) ? t + 1 : 0;
            const float4* s4 = (const float4*)(sT + (tn*64 + gb)*128 + gm);
            sv0 = s4[0]; sv1 = s4[1]; sv2 = s4[2]; sv3 = s4[3];
            skv = SK[(j*128 + tn)*64 + gb];
            #pragma unroll
            for (int r = 0; r < 16; ++r) {
                const int brow = bt2*32 + 4*q + (r & 3) + 8*(r >> 2);
                wsv[r] = WsT[(tn*64 + brow)*128 + n];
            }
        }

        #pragma unroll
        for (int m = 1; m < 64; m <<= 1) ssq += __shfl_xor(ssq, m, 64);
        if (lane == 0) wred[wave] = ssq;
        __syncthreads();   // B2: AB writes + wred partials visible
        const float4 w0 = *(const float4*)(wred);
        const float4 w1 = *(const float4*)(wred + 4);
        inv_s = __builtin_amdgcn_rsqf(w0.x+w0.y+w0.z+w0.w + w1.x+w1.y+w1.z+w1.w);
    }

    // ---- h = inv * state (fp32 path), layout (b, j, m) ----
    #pragma unroll
    for (int r = 0; r < 16; ++r) {
        const int brow = bt2*32 + 4*q + (r & 3) + 8*(r >> 2);
        h_out[(brow*20 + j)*128 + n] = inv_s * xprev[r];
    }
}

// ---------------------------------------------------------------- final
__global__ __launch_bounds__(128) void final_kernel(
    const float* __restrict__ h, const float* __restrict__ qv,
    const float* __restrict__ a1v, const float* __restrict__ a2v,
    const float* __restrict__ Hw, const float* __restrict__ Hb,
    float* __restrict__ out)
{
    const int b   = blockIdx.x;
    const int tid = threadIdx.x;    // 128
    __shared__ float hb[20][128];
    __shared__ float ql[128];
    __shared__ float ul[128];
    __shared__ float pl[20];
    __shared__ float lgt[20];
    __shared__ float red1[2], red2[2];

    for (int jj = 0; jj < 20; ++jj) hb[jj][tid] = h[(b*20+jj)*128 + tid];
    ql[tid] = qv[b*128 + tid];
    __syncthreads();
    if (tid < 20) {
        float d = 0.f;
        for (int m = 0; m < 128; ++m) d += hb[tid][m] * ql[m];
        lgt[tid] = d;
    }
    __syncthreads();
    if (tid == 0) {
        float mx = lgt[0];
        for (int jj = 1; jj < 20; ++jj) mx = fmaxf(mx, lgt[jj]);
        float s = 0.f;
        for (int jj = 0; jj < 20; ++jj) { const float e = expf(lgt[jj]-mx); pl[jj] = e; s += e; }
        const float is = 1.f / s;
        for (int jj = 0; jj < 20; ++jj) pl[jj] *= is;
    }
    __syncthreads();
    float u = 0.f;
    for (int jj = 0; jj < 20; ++jj) u += pl[jj] * hb[jj][tid];
    ul[tid] = u;
    __syncthreads();
    float acc = ql[tid] + Hb[tid];
    const float4* hwr = (const float4*)(Hw + tid*128);
    for (int m4 = 0; m4 < 32; ++m4) {
        const float4 w = hwr[m4];
        acc += ul[m4*4]*w.x + ul[m4*4+1]*w.y + ul[m4*4+2]*w.z + ul[m4*4+3]*w.w;
    }
    const float r  = fmaxf(acc, 0.f);
    float y1 = r * a1v[b*128+tid];
    float y2 = r * a2v[b*128+tid];
    #pragma unroll
    for (int mask = 1; mask < 64; mask <<= 1) {
        y1 += __shfl_xor(y1, mask, 64);
        y2 += __shfl_xor(y2, mask, 64);
    }
    if ((tid & 63) == 0) { red1[tid>>6] = y1; red2[tid>>6] = y2; }
    __syncthreads();
    if (tid == 0) {
        const float z1 = red1[0] + red1[1];
        const float z2 = red2[0] + red2[1];
        const float mx = fmaxf(z1, z2);
        const float e1 = expf(z1-mx), e2 = expf(z2-mx);
        const float s  = e1 + e2;
        out[b*2+0] = e1 / s;
        out[b*2+1] = e2 / s;
    }
}

// ---------------------------------------------------------------- launch
extern "C" void kernel_launch(void* const* d_in, const int* in_sizes, int n_in,
                              void* d_out, int out_size, void* d_ws, size_t ws_size,
                              hipStream_t stream)
{
    const int*   ids  = (const int*)  d_in[0];
    const int*   ques = (const int*)  d_in[1];
    const int*   ans  = (const int*)  d_in[2];
    const float* E    = (const float*)d_in[3];
    const float* Uw   = (const float*)d_in[4];
    const float* Ubv  = (const float*)d_in[5];
    const float* Vw   = (const float*)d_in[6];
    const float* Vb   = (const float*)d_in[7];
    const float* Ww   = (const float*)d_in[8];
    const float* Wb   = (const float*)d_in[9];
    const float* sk   = (const float*)d_in[10];
    const float* Hw   = (const float*)d_in[11];
    const float* Hb   = (const float*)d_in[12];

    // workspace (floats): sT 1M | WsT 1M | vkey 2560 | qv/a1v/a2v 3*8192 | h 163840 | SK 163840
    float* ws   = (float*)d_ws;
    float* sT   = ws;
    float* WsT  = sT  + 1048576;
    float* vkey = WsT + 1048576;
    float* qv   = vkey + 2560;
    float* a1v  = qv  + 8192;
    float* a2v  = a1v + 8192;
    float* h    = a2v + 8192;
    float* SK   = h   + 163840;

    prep_kernel<<<1108, 128, 0, stream>>>(ids, ques, ans, E, Ww, Wb, Vw, Vb, sk,
                                          sT, WsT, vkey, qv, a1v, a2v, SK);
    scan_kernel<<<20, 512, 0, stream>>>(sT, WsT, vkey, Uw, Ubv, SK, h);
    final_kernel<<<64, 128, 0, stream>>>(h, qv, a1v, a2v, Hw, Hb, (float*)d_out);
}